// Round 12
// baseline (172.058 us; speedup 1.0000x reference)
//
#include <hip/hip_runtime.h>
#include <hip/hip_fp16.h>

// SoftFreezeAttention on MI355X (gfx950).
// out = softmax_rows(exp(-cdist(X,P)/efft)) @ V  with NO max-subtraction
// (reference underflows to 0: dist/temp ~ 800 -> exp = exact f32 zero; we
// still compute everything honestly).
//
// All-fp8 two-pass pipeline (chunks=1):
//   prep:  X->X8+x2, P->P8+p2, V->Vt8 (fp8, transposed, n-PERMUTED), invt
//   passA: fp8 GEMM X8.P8^T -> W8 = exp(-dist*invt), stored n-PERMUTED via
//          direct packed dword nt-stores (no LDS round-trip) + shfl rowsum
//   rowsum_k; passB: fp8 GEMM O^T = Vt8 . W8^T (contraction over permuted n
//          is invariant: both operands share the same permutation).
//
// Permutation pi (within each 64-col block): orig (nt*16+r15) -> r15*4+nt.
// Each lane's 4 nt-values for one row become 4 contiguous W bytes -> one
// dword store; quarter-wave = 64B contiguous. Kills pass A's f16 LDS
// round-trip epilogue (~550 -> ~350 instrs/thread, no LDS, no barriers).
//
// History: R5 233.75 -> R7 fp8 W (206) -> R10 2-phase dbuf (185.2) ->
// R11 all-fp8 K-loop (159.3; passA 95, passB ~52). R11 counters: bank
// conflicts 0->2^23 (b64 frag reads, +4cy each; deferred) and epilogue
// ~= K-loop in instr budget (this round's target).

typedef _Float16 f16;
typedef _Float16 f16x8 __attribute__((ext_vector_type(8)));
typedef float f32x4 __attribute__((ext_vector_type(4)));
typedef int i32x4 __attribute__((ext_vector_type(4)));
typedef unsigned char u8;

#define DEV __device__ __forceinline__

DEV void gload16(const void* g, void* l) {
  __builtin_amdgcn_global_load_lds(
      (const __attribute__((address_space(1))) void*)g,
      (__attribute__((address_space(3))) void*)l, 16, 0, 0);
}

// pack 4 f32 -> 4 fp8 e4m3 bytes (OCP), little-endian [a,b,c,d]
DEV int pack4_fp8(float a, float b, float c, float d) {
  int lo = __builtin_amdgcn_cvt_pk_fp8_f32(a, b, 0, false);
  int hi = __builtin_amdgcn_cvt_pk_fp8_f32(c, d, 0, false);
  return (hi << 16) | (lo & 0xffff);
}

// ---------------------------------------------------------------- prep kernels

// one wave per row of 512 f32: pack to fp8 + sum of squares (f32)
__global__ __launch_bounds__(256) void prep_rows8(const float* __restrict__ src,
                                                  u8* __restrict__ dst,
                                                  float* __restrict__ sq) {
  int row  = blockIdx.x * 4 + (threadIdx.x >> 6);
  int lane = threadIdx.x & 63;
  const float* r = src + (size_t)row * 512 + lane * 8;
  float4 a = *(const float4*)r;
  float4 b = *(const float4*)(r + 4);
  int2 pk;
  pk.x = pack4_fp8(a.x, a.y, a.z, a.w);
  pk.y = pack4_fp8(b.x, b.y, b.z, b.w);
  *(int2*)(dst + (size_t)row * 512 + lane * 8) = pk;
  float ss = a.x*a.x + a.y*a.y + a.z*a.z + a.w*a.w
           + b.x*b.x + b.y*b.y + b.z*b.z + b.w*b.w;
  ss += __shfl_xor(ss, 1);  ss += __shfl_xor(ss, 2);  ss += __shfl_xor(ss, 4);
  ss += __shfl_xor(ss, 8);  ss += __shfl_xor(ss, 16); ss += __shfl_xor(ss, 32);
  if (lane == 0) sq[row] = ss;
}

__global__ __launch_bounds__(256) void prep_invt(const float* __restrict__ T,
                                                 const float* __restrict__ ns,
                                                 float* __restrict__ invt) {
  int i = blockIdx.x * 256 + threadIdx.x;
  invt[i] = 1.0f / ((fabsf(T[i]) + 0.1f) * ns[i]);
}

// V [4096][512] f32 -> Vt8 [512][4096] fp8, columns stored in pi order:
// Vt8[d][b*64 + r*4 + nt] = fp8(V[b*64 + nt*16 + r][d]).
// Dest byte q (block-local): source n-local = (q&3)*16 + (q>>2).
__global__ __launch_bounds__(256) void prep_vt(const float* __restrict__ V,
                                               u8* __restrict__ Vt) {
  __shared__ f16 T[64][72];
  int n0 = blockIdx.x * 64, d0 = blockIdx.y * 64;
  int t = threadIdx.x;
#pragma unroll
  for (int rr = 0; rr < 4; ++rr) {
    int r  = (t >> 4) + rr * 16;
    int cq = t & 15;
    float4 v = *(const float4*)(V + (size_t)(n0 + r) * 512 + d0 + cq * 4);
    T[cq*4+0][r] = (f16)v.x; T[cq*4+1][r] = (f16)v.y;
    T[cq*4+2][r] = (f16)v.z; T[cq*4+3][r] = (f16)v.w;
  }
  __syncthreads();
  int rd = t >> 2, part = t & 3;   // dest 16B chunk: q = part*16 + i
  int p4 = part * 4;
  i32x4 pk;
  // byte i: src = (i&3)*16 + p4 + (i>>2)
  pk.x = pack4_fp8((float)T[rd][p4+0], (float)T[rd][16+p4+0],
                   (float)T[rd][32+p4+0], (float)T[rd][48+p4+0]);
  pk.y = pack4_fp8((float)T[rd][p4+1], (float)T[rd][16+p4+1],
                   (float)T[rd][32+p4+1], (float)T[rd][48+p4+1]);
  pk.z = pack4_fp8((float)T[rd][p4+2], (float)T[rd][16+p4+2],
                   (float)T[rd][32+p4+2], (float)T[rd][48+p4+2]);
  pk.w = pack4_fp8((float)T[rd][p4+3], (float)T[rd][16+p4+3],
                   (float)T[rd][32+p4+3], (float)T[rd][48+p4+3]);
  *(i32x4*)(Vt + (size_t)(d0 + rd) * 4096 + n0 + part * 16) = pk;
}

// ------------------------------------------------- main GEMM (C = A . B^T form)
// All-fp8. 128x128 tile, 4 waves 2x2, 4x4 16x16x32 frags/wave.
// K-tile = 128 B = 128 fp8. LDS dbuf 64KB. Tiles [128 r][128 B]; 16B-chunk o
// of row r stored at o^(r&7); global_load_lds w/ pre-swizzled source.
// 2-phase: stage(next) issued BEFORE compute(cur), one barrier/iter.
// 1-D grid + bijective XCD swizzle.
template <int EPI>
__global__ __launch_bounds__(256) void gemm_bt(
    const void* __restrict__ A, const void* __restrict__ B, int Kb, int gx,
    const float* __restrict__ x2, const float* __restrict__ p2,
    const float* __restrict__ invt, u8* __restrict__ Wout,
    float* __restrict__ Wpart,
    const float* __restrict__ rowsum, float* __restrict__ outp) {
  __shared__ __align__(16) char smem[65536];
  char* As = smem;            // +cur: 0 or 32768
  char* Bs = smem + 16384;

  const int nwg = gridDim.x;
  const int sid = (blockIdx.x & 7) * (nwg >> 3) + (blockIdx.x >> 3);
  const int bx = sid % gx, by = sid / gx;

  const int tid = threadIdx.x, lane = tid & 63, w = tid >> 6;
  const int wrow = (w >> 1) * 64, wcol = (w & 1) * 64;
  const int g = lane >> 4, r15 = lane & 15;
  const int m0 = by * 128, n0 = bx * 128;

  const char* Ablk = (const char*)A + (size_t)m0 * Kb;
  const char* Bblk = (const char*)B + (size_t)n0 * Kb;

  const int lr = lane >> 3;
  const int lo = (lane & 7) ^ lr;
  const char* aSrc[4]; const char* bSrc[4]; char* aDst[4]; char* bDst[4];
#pragma unroll
  for (int i = 0; i < 4; ++i) {
    int cb  = w * 4 + i;
    int row = cb * 8 + lr;
    aSrc[i] = Ablk + (size_t)row * Kb + 16 * lo;
    bSrc[i] = Bblk + (size_t)row * Kb + 16 * lo;
    aDst[i] = As + cb * 1024;
    bDst[i] = Bs + cb * 1024;
  }

  int abase[4], asw[4], bbase[4], bsw[4];
#pragma unroll
  for (int mt = 0; mt < 4; ++mt) {
    int r = wrow + mt * 16 + r15;
    abase[mt] = r * 128; asw[mt] = (r & 7) << 4;
    int rb = wcol + mt * 16 + r15;
    bbase[mt] = rb * 128; bsw[mt] = (rb & 7) << 4;
  }

  f32x4 acc[4][4] = {};

  const int NIT = Kb >> 7;
#pragma unroll
  for (int i = 0; i < 4; ++i) gload16(aSrc[i], aDst[i]);
#pragma unroll
  for (int i = 0; i < 4; ++i) gload16(bSrc[i], bDst[i]);
  __syncthreads();

#pragma unroll 2
  for (int it = 0; it < NIT; ++it) {
    const int cur = (it & 1) << 15;
    const int nxt = cur ^ 32768;
    if (it + 1 < NIT) {                    // issue next-tile loads FIRST
      const int kb1 = (it + 1) << 7;
#pragma unroll
      for (int i = 0; i < 4; ++i) gload16(aSrc[i] + kb1, aDst[i] + nxt);
#pragma unroll
      for (int i = 0; i < 4; ++i) gload16(bSrc[i] + kb1, bDst[i] + nxt);
    }
    const char* As_ = As + cur;
    const char* Bs_ = Bs + cur;
#pragma unroll
    for (int ks = 0; ks < 4; ++ks) {       // 4 k-slices of K=32 fp8
      long aL[4], bL[4];
#pragma unroll
      for (int mt = 0; mt < 4; ++mt)
        aL[mt] = *(const long*)(As_ + (abase[mt] + ((32 * ks + 8 * g) ^ asw[mt])));
#pragma unroll
      for (int nt = 0; nt < 4; ++nt)
        bL[nt] = *(const long*)(Bs_ + (bbase[nt] + ((32 * ks + 8 * g) ^ bsw[nt])));
#pragma unroll
      for (int mt = 0; mt < 4; ++mt)
#pragma unroll
        for (int nt = 0; nt < 4; ++nt)
          acc[mt][nt] = __builtin_amdgcn_mfma_f32_16x16x32_fp8_fp8(aL[mt], bL[nt],
                                                                   acc[mt][nt], 0, 0, 0);
    }
    __syncthreads();
  }

  if constexpr (EPI == 0) {
    // ---- pass A epilogue (no LDS): per (mt,reg): 4 exps -> pack4 -> one
    // permuted nt dword store (row m, cols pi: wcol+4*r15+nt) + shfl rowsum.
    float p2v[4], itv[4];
#pragma unroll
    for (int nt = 0; nt < 4; ++nt) {
      int n = n0 + wcol + nt * 16 + r15;
      p2v[nt] = p2[n]; itv[nt] = invt[n];
    }
#pragma unroll
    for (int mt = 0; mt < 4; ++mt) {
#pragma unroll
      for (int reg = 0; reg < 4; ++reg) {
        int ml = wrow + mt * 16 + g * 4 + reg;
        float xx = x2[m0 + ml];
        float wv[4];
#pragma unroll
        for (int nt = 0; nt < 4; ++nt) {
          float d2 = xx + p2v[nt] - 2.0f * acc[mt][nt][reg];
          float dist = __builtin_amdgcn_sqrtf(fmaxf(d2, 0.0f));
          wv[nt] = __expf(-dist * itv[nt]);
        }
        int dw = pack4_fp8(wv[0], wv[1], wv[2], wv[3]);
        __builtin_nontemporal_store(
            dw, (int*)(Wout + (size_t)(m0 + ml) * 4096 + n0 + wcol + 4 * r15));
        float rs = wv[0] + wv[1] + wv[2] + wv[3];
        rs += __shfl_xor(rs, 1); rs += __shfl_xor(rs, 2);
        rs += __shfl_xor(rs, 4); rs += __shfl_xor(rs, 8);
        if (r15 == 0) Wpart[(size_t)(m0 + ml) * 64 + bx * 2 + (w & 1)] = rs;
      }
    }
  } else {
    // ---- pass B epilogue: O^T transpose via per-wave LDS + normalize
    float* Tb = (float*)(smem) + w * (32 * 66);
    const int dl = lane & 31, half = lane >> 5;
#pragma unroll
    for (int h = 0; h < 2; ++h) {
#pragma unroll
      for (int mh = 0; mh < 2; ++mh) {
        int mt = h * 2 + mh;
#pragma unroll
        for (int nt = 0; nt < 4; ++nt)
#pragma unroll
          for (int reg = 0; reg < 4; ++reg)
            Tb[(mh * 16 + g * 4 + reg) * 66 + nt * 16 + r15] = acc[mt][nt][reg];
      }
#pragma unroll
      for (int rr = 0; rr < 32; ++rr) {
        int mloc = rr * 2 + half;
        float v = Tb[dl * 66 + mloc];
        int mg = n0 + wcol + mloc;
        int dg = m0 + wrow + h * 32 + dl;
        float nrm = 1.0f / (rowsum[mg] + 1e-8f);
        __builtin_nontemporal_store(v * nrm, &outp[(size_t)mg * 512 + dg]);
      }
      __syncthreads();  // Tb reused next h
    }
  }
}

// rowsum[m] = sum of 64 partials
__global__ __launch_bounds__(256) void rowsum_k(const float* __restrict__ Wpart,
                                                float* __restrict__ rowsum) {
  int row  = blockIdx.x * 4 + (threadIdx.x >> 6);
  int lane = threadIdx.x & 63;
  float v = Wpart[(size_t)row * 64 + lane];
  v += __shfl_xor(v, 1);  v += __shfl_xor(v, 2);  v += __shfl_xor(v, 4);
  v += __shfl_xor(v, 8);  v += __shfl_xor(v, 16); v += __shfl_xor(v, 32);
  if (lane == 0) rowsum[row] = v;
}

// ---------------------------------------------------------------------- launch

extern "C" void kernel_launch(void* const* d_in, const int* in_sizes, int n_in,
                              void* d_out, int out_size, void* d_ws, size_t ws_size,
                              hipStream_t stream) {
  const float* x   = (const float*)d_in[0];
  const float* pos = (const float*)d_in[1];
  const float* val = (const float*)d_in[2];
  const float* tmp = (const float*)d_in[3];
  const float* nsc = (const float*)d_in[4];
  float* out = (float*)d_out;

  char* p = (char*)d_ws;
  u8*    X8     = (u8*)p;    p += (size_t)16384 * 512;
  u8*    P8     = (u8*)p;    p += (size_t)4096 * 512;
  u8*    Vt8    = (u8*)p;    p += (size_t)512 * 4096;
  float* x2     = (float*)p; p += (size_t)16384 * 4;
  float* p2     = (float*)p; p += (size_t)4096 * 4;
  float* invt   = (float*)p; p += (size_t)4096 * 4;
  float* rowsum = (float*)p; p += (size_t)16384 * 4;
  float* Wpart  = (float*)p; p += (size_t)16384 * 64 * 4;
  u8*    W8     = (u8*)p;
  size_t fixed  = (size_t)(p - (char*)d_ws);
  size_t wfull  = (size_t)16384 * 4096;   // fp8 W

  int chunks = 1;
  while (chunks < 16 && fixed + wfull / chunks > ws_size) chunks <<= 1;
  if (fixed + wfull / chunks > ws_size) return;
  int Mc = 16384 / chunks;

  prep_rows8<<<4096, 256, 0, stream>>>(x, X8, x2);
  prep_rows8<<<1024, 256, 0, stream>>>(pos, P8, p2);
  prep_invt<<<16, 256, 0, stream>>>(tmp, nsc, invt);
  prep_vt<<<dim3(64, 8), 256, 0, stream>>>(val, Vt8);

  for (int c = 0; c < chunks; ++c) {
    // pass A: Kb = 512 fp8 bytes/row, NIT = 4
    gemm_bt<0><<<32 * (Mc / 128), 256, 0, stream>>>(
        X8 + (size_t)c * Mc * 512, P8, 512, 32,
        x2 + (size_t)c * Mc, p2, invt, W8 + (size_t)c * Mc * 4096,
        Wpart + (size_t)c * Mc * 64, nullptr, nullptr);
    rowsum_k<<<Mc / 4, 256, 0, stream>>>(Wpart + (size_t)c * Mc * 64,
                                         rowsum + (size_t)c * Mc);
    // pass B: Kb = 4096 fp8 bytes/row, NIT = 32
    gemm_bt<1><<<(Mc / 128) * 4, 256, 0, stream>>>(
        Vt8, W8 + (size_t)c * Mc * 4096, 4096, Mc / 128,
        nullptr, nullptr, nullptr, nullptr, nullptr,
        rowsum + (size_t)c * Mc, out + (size_t)c * Mc * 512);
  }
}

// Round 13
// 165.051 us; speedup vs baseline: 1.0425x; 1.0425x over previous
//
#include <hip/hip_runtime.h>
#include <hip/hip_fp16.h>

// SoftFreezeAttention on MI355X (gfx950).
// out = softmax_rows(exp(-cdist(X,P)/efft)) @ V  with NO max-subtraction
// (reference underflows to 0; computed honestly).
//
// All-fp8 two-pass pipeline (chunks=1):
//   prep:  X->X8+x2, P->P8+p2, V->Vt8 (fp8, transposed), invt
//   passA: fp8 GEMM X8.P8^T -> W8 = exp(-dist*invt) via f16 LDS tile,
//          coalesced nt int4 stores + readback rowsum partials
//   rowsum_k; passB: fp8 GEMM O^T = Vt8 . W8^T, transpose + normalize.
//
// History: R5 233.75 -> R7 fp8 W (206) -> R10 2-phase dbuf (185.2) ->
// R11 all-fp8 (159.3) -> R12 permuted-store epilogue REGRESSED (172,
// shfl on LDS pipe + scattered stores) -> reverted.
// R13: bank-conflict fix. b64 frag reads issue per quarter-wave (16 lanes
// x 8B = 128B); half-bit (g&1) was constant across the quarter-wave ->
// only 16 banks used -> 2-way conflict (the 8.4M counter). Fix: PARITY
// HALF-SWAP — rows with (row>>3)&1 store each 16B granule's 8B halves
// swapped (producers: prep_rows8, prep_vt, W8 store), reads XOR (r&8).
// Bank = 4*(gl^r7) + 2*((g&1)^(r15>>3)): 16 lanes -> 32 banks, 0-conflict.
// 16B granules intact -> global_load_lds staging unchanged.

typedef _Float16 f16;
typedef _Float16 f16x8 __attribute__((ext_vector_type(8)));
typedef float f32x4 __attribute__((ext_vector_type(4)));
typedef int i32x4 __attribute__((ext_vector_type(4)));
typedef unsigned char u8;

#define DEV __device__ __forceinline__

DEV void gload16(const void* g, void* l) {
  __builtin_amdgcn_global_load_lds(
      (const __attribute__((address_space(1))) void*)g,
      (__attribute__((address_space(3))) void*)l, 16, 0, 0);
}

// pack 4 f32 -> 4 fp8 e4m3 bytes (OCP), little-endian [a,b,c,d]
DEV int pack4_fp8(float a, float b, float c, float d) {
  int lo = __builtin_amdgcn_cvt_pk_fp8_f32(a, b, 0, false);
  int hi = __builtin_amdgcn_cvt_pk_fp8_f32(c, d, 0, false);
  return (hi << 16) | (lo & 0xffff);
}

// ---------------------------------------------------------------- prep kernels

// one wave per row of 512 f32: pack to fp8 + sum of squares.
// Rows with (row>>3)&1: 8B halves of each 16B granule stored swapped.
__global__ __launch_bounds__(256) void prep_rows8(const float* __restrict__ src,
                                                  u8* __restrict__ dst,
                                                  float* __restrict__ sq) {
  int row  = blockIdx.x * 4 + (threadIdx.x >> 6);
  int lane = threadIdx.x & 63;
  const float* r = src + (size_t)row * 512 + lane * 8;
  float4 a = *(const float4*)r;
  float4 b = *(const float4*)(r + 4);
  int2 pk;
  pk.x = pack4_fp8(a.x, a.y, a.z, a.w);
  pk.y = pack4_fp8(b.x, b.y, b.z, b.w);
  int sw = ((row >> 3) & 1) << 3;          // parity half-swap
  *(int2*)(dst + (size_t)row * 512 + ((lane * 8) ^ sw)) = pk;
  float ss = a.x*a.x + a.y*a.y + a.z*a.z + a.w*a.w
           + b.x*b.x + b.y*b.y + b.z*b.z + b.w*b.w;
  ss += __shfl_xor(ss, 1);  ss += __shfl_xor(ss, 2);  ss += __shfl_xor(ss, 4);
  ss += __shfl_xor(ss, 8);  ss += __shfl_xor(ss, 16); ss += __shfl_xor(ss, 32);
  if (lane == 0) sq[row] = ss;
}

__global__ __launch_bounds__(256) void prep_invt(const float* __restrict__ T,
                                                 const float* __restrict__ ns,
                                                 float* __restrict__ invt) {
  int i = blockIdx.x * 256 + threadIdx.x;
  invt[i] = 1.0f / ((fabsf(T[i]) + 0.1f) * ns[i]);
}

// V [4096][512] f32 -> Vt8 [512][4096] fp8, 64x64 tiles via LDS.
// Rows (d) with (d>>3)&1: granule halves swapped.
__global__ __launch_bounds__(256) void prep_vt(const float* __restrict__ V,
                                               u8* __restrict__ Vt) {
  __shared__ f16 T[64][72];
  int n0 = blockIdx.x * 64, d0 = blockIdx.y * 64;
  int t = threadIdx.x;
#pragma unroll
  for (int rr = 0; rr < 4; ++rr) {
    int r  = (t >> 4) + rr * 16;
    int cq = t & 15;
    float4 v = *(const float4*)(V + (size_t)(n0 + r) * 512 + d0 + cq * 4);
    T[cq*4+0][r] = (f16)v.x; T[cq*4+1][r] = (f16)v.y;
    T[cq*4+2][r] = (f16)v.z; T[cq*4+3][r] = (f16)v.w;
  }
  __syncthreads();
  int rd = t >> 2, part = t & 3;
  f16x8 o0 = *(const f16x8*)&T[rd][part * 16];
  f16x8 o1 = *(const f16x8*)&T[rd][part * 16 + 8];
  i32x4 pk;
  pk.x = pack4_fp8((float)o0[0], (float)o0[1], (float)o0[2], (float)o0[3]);
  pk.y = pack4_fp8((float)o0[4], (float)o0[5], (float)o0[6], (float)o0[7]);
  pk.z = pack4_fp8((float)o1[0], (float)o1[1], (float)o1[2], (float)o1[3]);
  pk.w = pack4_fp8((float)o1[4], (float)o1[5], (float)o1[6], (float)o1[7]);
  int swp = (rd >> 3) & 1;
  i32x4 outv;
  outv.x = swp ? pk.z : pk.x;  outv.y = swp ? pk.w : pk.y;
  outv.z = swp ? pk.x : pk.z;  outv.w = swp ? pk.y : pk.w;
  *(i32x4*)(Vt + (size_t)(d0 + rd) * 4096 + n0 + part * 16) = outv;
}

// ------------------------------------------------- main GEMM (C = A . B^T form)
// All-fp8. 128x128 tile, 4 waves 2x2, 4x4 16x16x32 frags/wave.
// K-tile = 128 B. LDS dbuf 64KB. Granule o of row r stored at o^(r&7);
// 8B halves swapped for (r>>3)&1 rows (pre-applied by producers).
// Frag read offset = (32ks+8g) ^ [((r&7)<<4) | (r&8)]  -> 0-conflict b64.
// 2-phase: stage(next) issued BEFORE compute(cur), one barrier/iter.
// 1-D grid + bijective XCD swizzle.
template <int EPI>
__global__ __launch_bounds__(256) void gemm_bt(
    const void* __restrict__ A, const void* __restrict__ B, int Kb, int gx,
    const float* __restrict__ x2, const float* __restrict__ p2,
    const float* __restrict__ invt, u8* __restrict__ Wout,
    float* __restrict__ Wpart,
    const float* __restrict__ rowsum, float* __restrict__ outp) {
  __shared__ __align__(16) char smem[65536];
  char* As = smem;            // +cur: 0 or 32768
  char* Bs = smem + 16384;

  const int nwg = gridDim.x;
  const int sid = (blockIdx.x & 7) * (nwg >> 3) + (blockIdx.x >> 3);
  const int bx = sid % gx, by = sid / gx;

  const int tid = threadIdx.x, lane = tid & 63, w = tid >> 6;
  const int wrow = (w >> 1) * 64, wcol = (w & 1) * 64;
  const int g = lane >> 4, r15 = lane & 15;
  const int m0 = by * 128, n0 = bx * 128;

  const char* Ablk = (const char*)A + (size_t)m0 * Kb;
  const char* Bblk = (const char*)B + (size_t)n0 * Kb;

  const int lr = lane >> 3;
  const int lo = (lane & 7) ^ lr;
  const char* aSrc[4]; const char* bSrc[4]; char* aDst[4]; char* bDst[4];
#pragma unroll
  for (int i = 0; i < 4; ++i) {
    int cb  = w * 4 + i;
    int row = cb * 8 + lr;
    aSrc[i] = Ablk + (size_t)row * Kb + 16 * lo;
    bSrc[i] = Bblk + (size_t)row * Kb + 16 * lo;
    aDst[i] = As + cb * 1024;
    bDst[i] = Bs + cb * 1024;
  }

  // frag read bases; swizzle = granule XOR (bits 4-6) | parity half-swap (bit 3)
  int abase[4], asw[4], bbase[4], bsw[4];
#pragma unroll
  for (int mt = 0; mt < 4; ++mt) {
    int r = wrow + mt * 16 + r15;
    abase[mt] = r * 128; asw[mt] = ((r & 7) << 4) | (r & 8);
    int rb = wcol + mt * 16 + r15;
    bbase[mt] = rb * 128; bsw[mt] = ((rb & 7) << 4) | (rb & 8);
  }

  f32x4 acc[4][4] = {};

  const int NIT = Kb >> 7;
#pragma unroll
  for (int i = 0; i < 4; ++i) gload16(aSrc[i], aDst[i]);
#pragma unroll
  for (int i = 0; i < 4; ++i) gload16(bSrc[i], bDst[i]);
  __syncthreads();

#pragma unroll 2
  for (int it = 0; it < NIT; ++it) {
    const int cur = (it & 1) << 15;
    const int nxt = cur ^ 32768;
    if (it + 1 < NIT) {                    // issue next-tile loads FIRST
      const int kb1 = (it + 1) << 7;
#pragma unroll
      for (int i = 0; i < 4; ++i) gload16(aSrc[i] + kb1, aDst[i] + nxt);
#pragma unroll
      for (int i = 0; i < 4; ++i) gload16(bSrc[i] + kb1, bDst[i] + nxt);
    }
    const char* As_ = As + cur;
    const char* Bs_ = Bs + cur;
#pragma unroll
    for (int ks = 0; ks < 4; ++ks) {       // 4 k-slices of K=32 fp8
      long aL[4], bL[4];
#pragma unroll
      for (int mt = 0; mt < 4; ++mt)
        aL[mt] = *(const long*)(As_ + (abase[mt] + ((32 * ks + 8 * g) ^ asw[mt])));
#pragma unroll
      for (int nt = 0; nt < 4; ++nt)
        bL[nt] = *(const long*)(Bs_ + (bbase[nt] + ((32 * ks + 8 * g) ^ bsw[nt])));
#pragma unroll
      for (int mt = 0; mt < 4; ++mt)
#pragma unroll
        for (int nt = 0; nt < 4; ++nt)
          acc[mt][nt] = __builtin_amdgcn_mfma_f32_16x16x32_fp8_fp8(aL[mt], bL[nt],
                                                                   acc[mt][nt], 0, 0, 0);
    }
    __syncthreads();
  }

  if constexpr (EPI == 0) {
    // ---- pass A epilogue: wv = exp(-dist*invt) into f16 LDS tile
    // Wt[128][136] (pad 8, conflict-free readback), then per thread 64 f16 ->
    // sum (rowsum partial) + 4x i32x4 fp8 NT-stores (halves swapped for
    // (row>>3)&1 rows so pass B's frag reads decode correctly).
    f16* Wt = (f16*)smem;            // overlays dbuf
    int nloc[4]; float p2v[4], itv[4];
#pragma unroll
    for (int nt = 0; nt < 4; ++nt) {
      int nl = wcol + nt * 16 + r15;
      nloc[nt] = nl; p2v[nt] = p2[n0 + nl]; itv[nt] = invt[n0 + nl];
    }
#pragma unroll
    for (int mt = 0; mt < 4; ++mt) {
#pragma unroll
      for (int reg = 0; reg < 4; ++reg) {
        int ml = wrow + mt * 16 + g * 4 + reg;
        float xx = x2[m0 + ml];
#pragma unroll
        for (int nt = 0; nt < 4; ++nt) {
          float d2 = xx + p2v[nt] - 2.0f * acc[mt][nt][reg];
          float dist = __builtin_amdgcn_sqrtf(fmaxf(d2, 0.0f));
          float wv = __expf(-dist * itv[nt]);
          Wt[ml * 136 + nloc[nt]] = (f16)wv;
        }
      }
    }
    __syncthreads();
    {
      int r = tid >> 1, half = tid & 1;
      int swp = (r >> 3) & 1;          // parity half-swap for this W row
      const f16* srcp = Wt + r * 136 + half * 64;
      float s = 0.f;
      int wds[16];
#pragma unroll
      for (int i = 0; i < 8; ++i) {
        f16x8 v = *(const f16x8*)(srcp + i * 8);
        float f0=(float)v[0], f1=(float)v[1], f2=(float)v[2], f3=(float)v[3];
        float f4=(float)v[4], f5=(float)v[5], f6=(float)v[6], f7=(float)v[7];
        s += f0+f1+f2+f3+f4+f5+f6+f7;
        wds[i*2]   = pack4_fp8(f0, f1, f2, f3);
        wds[i*2+1] = pack4_fp8(f4, f5, f6, f7);
      }
      u8* dstp = Wout + (size_t)(m0 + r) * 4096 + n0 + half * 64;
#pragma unroll
      for (int q = 0; q < 4; ++q) {
        i32x4 st;
        st.x = swp ? wds[q*4+2] : wds[q*4+0];
        st.y = swp ? wds[q*4+3] : wds[q*4+1];
        st.z = swp ? wds[q*4+0] : wds[q*4+2];
        st.w = swp ? wds[q*4+1] : wds[q*4+3];
        __builtin_nontemporal_store(st, (i32x4*)(dstp + q * 16));
      }
      Wpart[(size_t)(m0 + r) * 64 + bx * 2 + half] = s;
    }
  } else {
    // ---- pass B epilogue: O^T transpose via per-wave LDS + normalize
    float* Tb = (float*)(smem) + w * (32 * 66);
    const int dl = lane & 31, half = lane >> 5;
#pragma unroll
    for (int h = 0; h < 2; ++h) {
#pragma unroll
      for (int mh = 0; mh < 2; ++mh) {
        int mt = h * 2 + mh;
#pragma unroll
        for (int nt = 0; nt < 4; ++nt)
#pragma unroll
          for (int reg = 0; reg < 4; ++reg)
            Tb[(mh * 16 + g * 4 + reg) * 66 + nt * 16 + r15] = acc[mt][nt][reg];
      }
#pragma unroll
      for (int rr = 0; rr < 32; ++rr) {
        int mloc = rr * 2 + half;
        float v = Tb[dl * 66 + mloc];
        int mg = n0 + wcol + mloc;
        int dg = m0 + wrow + h * 32 + dl;
        float nrm = 1.0f / (rowsum[mg] + 1e-8f);
        __builtin_nontemporal_store(v * nrm, &outp[(size_t)mg * 512 + dg]);
      }
      __syncthreads();  // Tb reused next h
    }
  }
}

// rowsum[m] = sum of 64 partials
__global__ __launch_bounds__(256) void rowsum_k(const float* __restrict__ Wpart,
                                                float* __restrict__ rowsum) {
  int row  = blockIdx.x * 4 + (threadIdx.x >> 6);
  int lane = threadIdx.x & 63;
  float v = Wpart[(size_t)row * 64 + lane];
  v += __shfl_xor(v, 1);  v += __shfl_xor(v, 2);  v += __shfl_xor(v, 4);
  v += __shfl_xor(v, 8);  v += __shfl_xor(v, 16); v += __shfl_xor(v, 32);
  if (lane == 0) rowsum[row] = v;
}

// ---------------------------------------------------------------------- launch

extern "C" void kernel_launch(void* const* d_in, const int* in_sizes, int n_in,
                              void* d_out, int out_size, void* d_ws, size_t ws_size,
                              hipStream_t stream) {
  const float* x   = (const float*)d_in[0];
  const float* pos = (const float*)d_in[1];
  const float* val = (const float*)d_in[2];
  const float* tmp = (const float*)d_in[3];
  const float* nsc = (const float*)d_in[4];
  float* out = (float*)d_out;

  char* p = (char*)d_ws;
  u8*    X8     = (u8*)p;    p += (size_t)16384 * 512;
  u8*    P8     = (u8*)p;    p += (size_t)4096 * 512;
  u8*    Vt8    = (u8*)p;    p += (size_t)512 * 4096;
  float* x2     = (float*)p; p += (size_t)16384 * 4;
  float* p2     = (float*)p; p += (size_t)4096 * 4;
  float* invt   = (float*)p; p += (size_t)4096 * 4;
  float* rowsum = (float*)p; p += (size_t)16384 * 4;
  float* Wpart  = (float*)p; p += (size_t)16384 * 64 * 4;
  u8*    W8     = (u8*)p;
  size_t fixed  = (size_t)(p - (char*)d_ws);
  size_t wfull  = (size_t)16384 * 4096;   // fp8 W

  int chunks = 1;
  while (chunks < 16 && fixed + wfull / chunks > ws_size) chunks <<= 1;
  if (fixed + wfull / chunks > ws_size) return;
  int Mc = 16384 / chunks;

  prep_rows8<<<4096, 256, 0, stream>>>(x, X8, x2);
  prep_rows8<<<1024, 256, 0, stream>>>(pos, P8, p2);
  prep_invt<<<16, 256, 0, stream>>>(tmp, nsc, invt);
  prep_vt<<<dim3(64, 8), 256, 0, stream>>>(val, Vt8);

  for (int c = 0; c < chunks; ++c) {
    // pass A: Kb = 512 fp8 bytes/row, NIT = 4
    gemm_bt<0><<<32 * (Mc / 128), 256, 0, stream>>>(
        X8 + (size_t)c * Mc * 512, P8, 512, 32,
        x2 + (size_t)c * Mc, p2, invt, W8 + (size_t)c * Mc * 4096,
        Wpart + (size_t)c * Mc * 64, nullptr, nullptr);
    rowsum_k<<<Mc / 4, 256, 0, stream>>>(Wpart + (size_t)c * Mc * 64,
                                         rowsum + (size_t)c * Mc);
    // pass B: Kb = 4096 fp8 bytes/row, NIT = 32
    gemm_bt<1><<<(Mc / 128) * 4, 256, 0, stream>>>(
        Vt8, W8 + (size_t)c * Mc * 4096, 4096, Mc / 128,
        nullptr, nullptr, nullptr, nullptr, nullptr,
        rowsum + (size_t)c * Mc, out + (size_t)c * Mc * 512);
  }
}

// Round 14
// 154.376 us; speedup vs baseline: 1.1145x; 1.0691x over previous
//
#include <hip/hip_runtime.h>
#include <hip/hip_fp16.h>

// SoftFreezeAttention on MI355X (gfx950).
// out = softmax_rows(exp(-cdist(X,P)/efft)) @ V  with NO max-subtraction
// (reference underflows to 0; computed honestly).
//
// All-fp8 two-pass pipeline (chunks=1):
//   prep_all: X->X8+x2, P->P8+p2, V->Vt8 (fp8,transposed), invt  (1 launch)
//   passA: fp8 GEMM X8.P8^T -> W8 = exp(-dist*invt) via f16 LDS tile,
//          coalesced nt int4 stores + readback rowsum partials.
//          N-LOOP x4: each block does 4 n-tiles (grid 1024, amortizes
//          prologue + teardown; A restaged from L2).
//   rowsum_k; passB: fp8 GEMM O^T = Vt8 . W8^T, transpose + normalize.
//
// History: R5 233.75 -> R7 fp8 W (206) -> R10 2-phase dbuf (185.2) ->
// R11 all-fp8 (159.3, BEST) -> R12 permuted-store REGRESSED (172) ->
// R13 parity half-swap: conflicts 8.4M->0 but 2-way is FREE (G4/m136),
// and the swp-cndmask store broke write-combining (WRITE 82->181MB,
// passA +8.7us) -> REVERTED here. R14 = R11 core + prep fusion + N-loop.

typedef _Float16 f16;
typedef _Float16 f16x8 __attribute__((ext_vector_type(8)));
typedef float f32x4 __attribute__((ext_vector_type(4)));
typedef int i32x4 __attribute__((ext_vector_type(4)));
typedef unsigned char u8;

#define DEV __device__ __forceinline__

DEV void gload16(const void* g, void* l) {
  __builtin_amdgcn_global_load_lds(
      (const __attribute__((address_space(1))) void*)g,
      (__attribute__((address_space(3))) void*)l, 16, 0, 0);
}

// pack 4 f32 -> 4 fp8 e4m3 bytes (OCP), little-endian [a,b,c,d]
DEV int pack4_fp8(float a, float b, float c, float d) {
  int lo = __builtin_amdgcn_cvt_pk_fp8_f32(a, b, 0, false);
  int hi = __builtin_amdgcn_cvt_pk_fp8_f32(c, d, 0, false);
  return (hi << 16) | (lo & 0xffff);
}

// ---------------------------------------------------------------- fused prep

// rows: 4 per block, one wave each: pack 512 f32 -> fp8 + sum-of-squares
DEV void row_pack(const float* __restrict__ src, u8* __restrict__ dst,
                  float* __restrict__ sq, int blk) {
  int row  = blk * 4 + (threadIdx.x >> 6);
  int lane = threadIdx.x & 63;
  const float* r = src + (size_t)row * 512 + lane * 8;
  float4 a = *(const float4*)r;
  float4 b = *(const float4*)(r + 4);
  int2 pk;
  pk.x = pack4_fp8(a.x, a.y, a.z, a.w);
  pk.y = pack4_fp8(b.x, b.y, b.z, b.w);
  *(int2*)(dst + (size_t)row * 512 + lane * 8) = pk;
  float ss = a.x*a.x + a.y*a.y + a.z*a.z + a.w*a.w
           + b.x*b.x + b.y*b.y + b.z*b.z + b.w*b.w;
  ss += __shfl_xor(ss, 1);  ss += __shfl_xor(ss, 2);  ss += __shfl_xor(ss, 4);
  ss += __shfl_xor(ss, 8);  ss += __shfl_xor(ss, 16); ss += __shfl_xor(ss, 32);
  if (lane == 0) sq[row] = ss;
}

__global__ __launch_bounds__(256) void prep_all(
    const float* __restrict__ x, const float* __restrict__ pos,
    const float* __restrict__ val, const float* __restrict__ T,
    const float* __restrict__ ns,
    u8* __restrict__ X8, u8* __restrict__ P8, u8* __restrict__ Vt8,
    float* __restrict__ x2, float* __restrict__ p2,
    float* __restrict__ invt) {
  __shared__ f16 Tt[64][72];
  int b = blockIdx.x;
  if (b < 4096) {                      // X: 16384 rows
    row_pack(x, X8, x2, b);
  } else if (b < 5120) {               // P: 4096 rows
    row_pack(pos, P8, p2, b - 4096);
  } else if (b < 5632) {               // Vt: 512 64x64 tiles
    int id = b - 5120;
    int n0 = (id & 63) * 64, d0 = (id >> 6) * 64;
    int t = threadIdx.x;
#pragma unroll
    for (int rr = 0; rr < 4; ++rr) {
      int r  = (t >> 4) + rr * 16;
      int cq = t & 15;
      float4 v = *(const float4*)(val + (size_t)(n0 + r) * 512 + d0 + cq * 4);
      Tt[cq*4+0][r] = (f16)v.x; Tt[cq*4+1][r] = (f16)v.y;
      Tt[cq*4+2][r] = (f16)v.z; Tt[cq*4+3][r] = (f16)v.w;
    }
    __syncthreads();
    int rd = t >> 2, part = t & 3;
    f16x8 o0 = *(const f16x8*)&Tt[rd][part * 16];
    f16x8 o1 = *(const f16x8*)&Tt[rd][part * 16 + 8];
    i32x4 pk;
    pk.x = pack4_fp8((float)o0[0], (float)o0[1], (float)o0[2], (float)o0[3]);
    pk.y = pack4_fp8((float)o0[4], (float)o0[5], (float)o0[6], (float)o0[7]);
    pk.z = pack4_fp8((float)o1[0], (float)o1[1], (float)o1[2], (float)o1[3]);
    pk.w = pack4_fp8((float)o1[4], (float)o1[5], (float)o1[6], (float)o1[7]);
    *(i32x4*)(Vt8 + (size_t)(d0 + rd) * 4096 + n0 + part * 16) = pk;
  } else {                             // invt: 16 blocks x 256
    int i = (b - 5632) * 256 + threadIdx.x;
    invt[i] = 1.0f / ((fabsf(T[i]) + 0.1f) * ns[i]);
  }
}

// ------------------------------------------------- main GEMM (C = A . B^T form)
// All-fp8. 128x128 tile, 4 waves 2x2, 4x4 16x16x32 frags/wave.
// K-tile = 128 B = 128 fp8. LDS dbuf 64KB. Tiles [128 r][128 B]; 16B-chunk o
// of row r stored at o^(r&7); global_load_lds w/ pre-swizzled source.
// 2-phase: stage(next) issued BEFORE compute(cur), one barrier/iter.
// EPI 0: N-LOOP nrep=4 (bxj = bx*4+j), full K-loop + epilogue per n-tile.
// 1-D grid + bijective XCD swizzle.
template <int EPI>
__global__ __launch_bounds__(256) void gemm_bt(
    const void* __restrict__ A, const void* __restrict__ B, int Kb, int gx,
    const float* __restrict__ x2, const float* __restrict__ p2,
    const float* __restrict__ invt, u8* __restrict__ Wout,
    float* __restrict__ Wpart,
    const float* __restrict__ rowsum, float* __restrict__ outp) {
  __shared__ __align__(16) char smem[65536];
  char* As = smem;            // +cur: 0 or 32768
  char* Bs = smem + 16384;

  const int nwg = gridDim.x;
  const int sid = (blockIdx.x & 7) * (nwg >> 3) + (blockIdx.x >> 3);
  const int bx = sid % gx, by = sid / gx;

  const int tid = threadIdx.x, lane = tid & 63, w = tid >> 6;
  const int wrow = (w >> 1) * 64, wcol = (w & 1) * 64;
  const int g = lane >> 4, r15 = lane & 15;
  const int m0 = by * 128;

  const char* Ablk = (const char*)A + (size_t)m0 * Kb;

  const int lr = lane >> 3;
  const int lo = (lane & 7) ^ lr;
  const char* aSrc[4]; char* aDst[4]; char* bDst[4];
  int srow[4];
#pragma unroll
  for (int i = 0; i < 4; ++i) {
    int cb  = w * 4 + i;
    srow[i] = cb * 8 + lr;
    aSrc[i] = Ablk + (size_t)srow[i] * Kb + 16 * lo;
    aDst[i] = As + cb * 1024;
    bDst[i] = Bs + cb * 1024;
  }

  int abase[4], asw[4], bbase[4], bsw[4];
#pragma unroll
  for (int mt = 0; mt < 4; ++mt) {
    int r = wrow + mt * 16 + r15;
    abase[mt] = r * 128; asw[mt] = (r & 7) << 4;
    int rb = wcol + mt * 16 + r15;
    bbase[mt] = rb * 128; bsw[mt] = (rb & 7) << 4;
  }

  const int NIT = Kb >> 7;
  constexpr int nrep = (EPI == 0) ? 4 : 1;

  for (int j = 0; j < nrep; ++j) {
    const int bxj = bx * nrep + j;
    const int n0 = bxj * 128;
    const char* Bblk = (const char*)B + (size_t)n0 * Kb;
    const char* bSrc[4];
#pragma unroll
    for (int i = 0; i < 4; ++i)
      bSrc[i] = Bblk + (size_t)srow[i] * Kb + 16 * lo;

    __syncthreads();              // smem safe to reuse (Wt readers done)
    f32x4 acc[4][4] = {};
#pragma unroll
    for (int i = 0; i < 4; ++i) gload16(aSrc[i], aDst[i]);
#pragma unroll
    for (int i = 0; i < 4; ++i) gload16(bSrc[i], bDst[i]);
    __syncthreads();

#pragma unroll 2
    for (int it = 0; it < NIT; ++it) {
      const int cur = (it & 1) << 15;
      const int nxt = cur ^ 32768;
      if (it + 1 < NIT) {                  // issue next-tile loads FIRST
        const int kb1 = (it + 1) << 7;
#pragma unroll
        for (int i = 0; i < 4; ++i) gload16(aSrc[i] + kb1, aDst[i] + nxt);
#pragma unroll
        for (int i = 0; i < 4; ++i) gload16(bSrc[i] + kb1, bDst[i] + nxt);
      }
      const char* As_ = As + cur;
      const char* Bs_ = Bs + cur;
#pragma unroll
      for (int ks = 0; ks < 4; ++ks) {     // 4 k-slices of K=32 fp8
        long aL[4], bL[4];
#pragma unroll
        for (int mt = 0; mt < 4; ++mt)
          aL[mt] = *(const long*)(As_ + (abase[mt] + ((32 * ks + 8 * g) ^ asw[mt])));
#pragma unroll
        for (int nt = 0; nt < 4; ++nt)
          bL[nt] = *(const long*)(Bs_ + (bbase[nt] + ((32 * ks + 8 * g) ^ bsw[nt])));
#pragma unroll
        for (int mt = 0; mt < 4; ++mt)
#pragma unroll
          for (int nt = 0; nt < 4; ++nt)
            acc[mt][nt] = __builtin_amdgcn_mfma_f32_16x16x32_fp8_fp8(aL[mt], bL[nt],
                                                                     acc[mt][nt], 0, 0, 0);
      }
      __syncthreads();
    }

    if constexpr (EPI == 0) {
      // ---- pass A epilogue: wv = exp(-dist*invt) into f16 LDS tile
      // Wt[128][136] (pad 8, conflict-free readback), then per thread
      // 64 f16 -> sum (rowsum partial) + 4x i32x4 fp8 NT-stores.
      f16* Wt = (f16*)smem;            // overlays dbuf (post-barrier safe)
      int nloc[4]; float p2v[4], itv[4];
#pragma unroll
      for (int nt = 0; nt < 4; ++nt) {
        int nl = wcol + nt * 16 + r15;
        nloc[nt] = nl; p2v[nt] = p2[n0 + nl]; itv[nt] = invt[n0 + nl];
      }
#pragma unroll
      for (int mt = 0; mt < 4; ++mt) {
#pragma unroll
        for (int reg = 0; reg < 4; ++reg) {
          int ml = wrow + mt * 16 + g * 4 + reg;
          float xx = x2[m0 + ml];
#pragma unroll
          for (int nt = 0; nt < 4; ++nt) {
            float d2 = xx + p2v[nt] - 2.0f * acc[mt][nt][reg];
            float dist = __builtin_amdgcn_sqrtf(fmaxf(d2, 0.0f));
            float wv = __expf(-dist * itv[nt]);
            Wt[ml * 136 + nloc[nt]] = (f16)wv;
          }
        }
      }
      __syncthreads();
      {
        int r = tid >> 1, half = tid & 1;
        const f16* srcp = Wt + r * 136 + half * 64;
        float s = 0.f;
        int wds[16];
#pragma unroll
        for (int i = 0; i < 8; ++i) {
          f16x8 v = *(const f16x8*)(srcp + i * 8);
          float f0=(float)v[0], f1=(float)v[1], f2=(float)v[2], f3=(float)v[3];
          float f4=(float)v[4], f5=(float)v[5], f6=(float)v[6], f7=(float)v[7];
          s += f0+f1+f2+f3+f4+f5+f6+f7;
          wds[i*2]   = pack4_fp8(f0, f1, f2, f3);
          wds[i*2+1] = pack4_fp8(f4, f5, f6, f7);
        }
        u8* dstp = Wout + (size_t)(m0 + r) * 4096 + n0 + half * 64;
#pragma unroll
        for (int q = 0; q < 4; ++q) {
          i32x4 st = { wds[q*4], wds[q*4+1], wds[q*4+2], wds[q*4+3] };
          __builtin_nontemporal_store(st, (i32x4*)(dstp + q * 16));
        }
        Wpart[(size_t)(m0 + r) * 64 + bxj * 2 + half] = s;
      }
    } else {
      // ---- pass B epilogue: O^T transpose via per-wave LDS + normalize
      float* Tb = (float*)(smem) + w * (32 * 66);
      const int dl = lane & 31, half = lane >> 5;
#pragma unroll
      for (int h = 0; h < 2; ++h) {
#pragma unroll
        for (int mh = 0; mh < 2; ++mh) {
          int mt = h * 2 + mh;
#pragma unroll
          for (int nt = 0; nt < 4; ++nt)
#pragma unroll
            for (int reg = 0; reg < 4; ++reg)
              Tb[(mh * 16 + g * 4 + reg) * 66 + nt * 16 + r15] = acc[mt][nt][reg];
        }
#pragma unroll
        for (int rr = 0; rr < 32; ++rr) {
          int mloc = rr * 2 + half;
          float v = Tb[dl * 66 + mloc];
          int mg = n0 + wcol + mloc;
          int dg = m0 + wrow + h * 32 + dl;
          float nrm = 1.0f / (rowsum[mg] + 1e-8f);
          __builtin_nontemporal_store(v * nrm, &outp[(size_t)mg * 512 + dg]);
        }
        __syncthreads();  // Tb reused next h
      }
    }
  }
}

// rowsum[m] = sum of 64 partials
__global__ __launch_bounds__(256) void rowsum_k(const float* __restrict__ Wpart,
                                                float* __restrict__ rowsum) {
  int row  = blockIdx.x * 4 + (threadIdx.x >> 6);
  int lane = threadIdx.x & 63;
  float v = Wpart[(size_t)row * 64 + lane];
  v += __shfl_xor(v, 1);  v += __shfl_xor(v, 2);  v += __shfl_xor(v, 4);
  v += __shfl_xor(v, 8);  v += __shfl_xor(v, 16); v += __shfl_xor(v, 32);
  if (lane == 0) rowsum[row] = v;
}

// ---------------------------------------------------------------------- launch

extern "C" void kernel_launch(void* const* d_in, const int* in_sizes, int n_in,
                              void* d_out, int out_size, void* d_ws, size_t ws_size,
                              hipStream_t stream) {
  const float* x   = (const float*)d_in[0];
  const float* pos = (const float*)d_in[1];
  const float* val = (const float*)d_in[2];
  const float* tmp = (const float*)d_in[3];
  const float* nsc = (const float*)d_in[4];
  float* out = (float*)d_out;

  char* p = (char*)d_ws;
  u8*    X8     = (u8*)p;    p += (size_t)16384 * 512;
  u8*    P8     = (u8*)p;    p += (size_t)4096 * 512;
  u8*    Vt8    = (u8*)p;    p += (size_t)512 * 4096;
  float* x2     = (float*)p; p += (size_t)16384 * 4;
  float* p2     = (float*)p; p += (size_t)4096 * 4;
  float* invt   = (float*)p; p += (size_t)4096 * 4;
  float* rowsum = (float*)p; p += (size_t)16384 * 4;
  float* Wpart  = (float*)p; p += (size_t)16384 * 64 * 4;
  u8*    W8     = (u8*)p;
  size_t fixed  = (size_t)(p - (char*)d_ws);
  size_t wfull  = (size_t)16384 * 4096;   // fp8 W

  int chunks = 1;
  while (chunks < 16 && fixed + wfull / chunks > ws_size) chunks <<= 1;
  if (fixed + wfull / chunks > ws_size) return;
  int Mc = 16384 / chunks;

  prep_all<<<5648, 256, 0, stream>>>(x, pos, val, tmp, nsc,
                                     X8, P8, Vt8, x2, p2, invt);

  for (int c = 0; c < chunks; ++c) {
    // pass A: Kb = 512 fp8 bytes/row, NIT = 4, N-loop x4 -> grid 8*(Mc/128)
    gemm_bt<0><<<8 * (Mc / 128), 256, 0, stream>>>(
        X8 + (size_t)c * Mc * 512, P8, 512, 8,
        x2 + (size_t)c * Mc, p2, invt, W8 + (size_t)c * Mc * 4096,
        Wpart + (size_t)c * Mc * 64, nullptr, nullptr);
    rowsum_k<<<Mc / 4, 256, 0, stream>>>(Wpart + (size_t)c * Mc * 64,
                                         rowsum + (size_t)c * Mc);
    // pass B: Kb = 4096 fp8 bytes/row, NIT = 32
    gemm_bt<1><<<(Mc / 128) * 4, 256, 0, stream>>>(
        Vt8, W8 + (size_t)c * Mc * 4096, 4096, Mc / 128,
        nullptr, nullptr, nullptr, nullptr, nullptr,
        rowsum + (size_t)c * Mc, out + (size_t)c * Mc * 512);
  }
}